// Round 21
// baseline (300.042 us; speedup 1.0000x reference)
//
#include <hip/hip_runtime.h>

#define N_NODES 50000
#define N_EDGES 800000
#define N_GRAPHS 256
#define DIN 126
#define H 128
#define MP 50048           // N_NODES padded to 128
#define NBKT 196           // coarse buckets = dst>>8
#define NBA 100            // phase-A blocks
#define CHA 8000           // edges per phase-A block (100*8000 = 800000)
#define NSC 77             // ceil(NBKT*NBA/256) scan chunks
#define CABLK 3128         // (MP*16)/256 conv_A blocks
#define GSBLK 196          // ceil(N_NODES/256) gstart blocks

typedef __attribute__((ext_vector_type(8))) _Float16 half8v;
typedef __attribute__((ext_vector_type(4))) _Float16 half4v;
typedef __attribute__((ext_vector_type(4))) float f32x4;
typedef __attribute__((ext_vector_type(2))) float f32x2;

// ---------------------------------------------------------------------------
// Fused prep: blocks [0,768) convert W (3 layers); [768, 768+CABLK) convert
// layer-1 A (fp32 -> fp16, zero-padded); [768+CABLK, +GSBLK) build graph
// segment starts from the sorted batch vector.
// ---------------------------------------------------------------------------
struct WPtrs { const float* w[12]; };

__global__ __launch_bounds__(256) void conv_prep(WPtrs P, const float* __restrict__ X,
                                                 const int* __restrict__ batch,
                                                 _Float16* __restrict__ Wt16,
                                                 _Float16* __restrict__ A16,
                                                 int* __restrict__ gstart)
{
    if (blockIdx.x < 768) {
        const int t = blockIdx.x * 256 + threadIdx.x;
        const int layer = t >> 16;
        const int r = t & 65535;
        const int n = r >> 7, k = r & 127;
        const int mtx = n >> 7, cc = n & 127;
        const int Kd = (layer == 0) ? DIN : H;
        const float* W = P.w[layer * 4 + mtx];
        const float v = (k < Kd) ? W[(size_t)k * 128 + cc] : 0.f;
        Wt16[t] = (_Float16)v;
    } else if (blockIdx.x < 768 + CABLK) {
        const int t = (blockIdx.x - 768) * 256 + threadIdx.x;
        const int row = t >> 4;
        if (row >= MP) return;
        const int k0 = (t & 15) * 8;
        half8v v8;
        #pragma unroll
        for (int j = 0; j < 8; ++j) {
            const int k = k0 + j;
            float v = 0.f;
            if (row < N_NODES && k < DIN) v = X[(size_t)row * DIN + k];
            v8[j] = (_Float16)v;
        }
        *(half8v*)&A16[(size_t)row * 128 + k0] = v8;
    } else {
        const int n = (blockIdx.x - 768 - CABLK) * 256 + threadIdx.x;
        if (n >= N_NODES) return;
        const int b = batch[n];
        const int bp = (n == 0) ? -1 : batch[n - 1];
        for (int g = bp + 1; g <= b; ++g) gstart[g] = n;
        if (n == N_NODES - 1)
            for (int g = b + 1; g <= N_GRAPHS; ++g) gstart[g] = N_NODES;
    }
}

// ---------------------------------------------------------------------------
// MFMA GEMM (unchanged from R18/R20): one block = 64 rows x all 4 matrices,
// 512 threads, A staged once, LDS-staged dense epilogue.
// ---------------------------------------------------------------------------
__device__ __forceinline__ void dense_out512(const uint2 (&ldsO)[64][32],
                                             unsigned char* __restrict__ dst,
                                             int row0, int M, int t)
{
    #pragma unroll
    for (int i = 0; i < 2; ++i) {
        const int idx = i * 512 + t;
        const int rr = idx >> 4, c16 = idx & 15;
        const int ch = c16 ^ ((rr & 15) >> 1);
        const uint2 a = ldsO[rr][2 * ch];
        const uint2 b = ldsO[rr][2 * ch + 1];
        if (row0 + rr < M) {
            uint4 o;
            if (rr & 1) { o.x = b.x; o.y = b.y; o.z = a.x; o.w = a.y; }
            else        { o.x = a.x; o.y = a.y; o.z = b.x; o.w = b.y; }
            *(uint4*)(dst + (size_t)(row0 + rr) * 256 + c16 * 16) = o;
        }
    }
}

__device__ __forceinline__ void compute_acc16(const _Float16 (&ldsA)[2][64 * 64],
                                              const _Float16* __restrict__ Wt16,
                                              int mtx, int fr, int kq, int colbase,
                                              f32x4 (&acc)[4])
{
    #pragma unroll
    for (int step = 0; step < 4; ++step) {
        const int kg = step * 4 + kq;
        const int kh = kg >> 3, kk = kg & 7;
        half8v a[4];
        #pragma unroll
        for (int m = 0; m < 4; ++m) {
            const int ar = m * 16 + fr;
            const int slot = kk ^ (ar & 7);
            a[m] = *(const half8v*)&ldsA[kh][ar * 64 + slot * 8];
        }
        const size_t wo = (size_t)(mtx * 128 + colbase + fr) * 128 + kg * 8;
        const half8v w = *(const half8v*)&Wt16[wo];
        #pragma unroll
        for (int m = 0; m < 4; ++m)
            acc[m] = __builtin_amdgcn_mfma_f32_16x16x32_f16(w, a[m], acc[m], 0, 0, 0);
    }
}

__global__ __launch_bounds__(512) void gemm_mfma(
    const _Float16* __restrict__ A16, const _Float16* __restrict__ Wt16,
    const float* __restrict__ bias0, const float* __restrict__ bias1,
    const float* __restrict__ bias2, const float* __restrict__ bias3,
    _Float16* __restrict__ OEK, unsigned char* __restrict__ QV8,
    _Float16* __restrict__ OS, int M)
{
    __shared__ _Float16 ldsA[2][64 * 64];  // 16KB
    __shared__ uint2 ldsO[64][32];         // 16KB
    const int t = threadIdx.x;
    const int l = t & 63, w = t >> 6;
    const int row0 = blockIdx.x * 64;
    const int fr = l & 15;
    const int kq = l >> 4;
    const int colbase = w * 16;

    #pragma unroll
    for (int i = 0; i < 2; ++i) {
        const int gi = i * 512 + t;
        const int kh = gi >> 9;
        const int r = (gi >> 3) & 63;
        const int j = gi & 7;
        const int slot = j ^ (r & 7);
        *(half8v*)&ldsA[kh][r * 64 + slot * 8] =
            *(const half8v*)&A16[(size_t)(row0 + r) * 128 + kh * 64 + j * 8];
    }
    __syncthreads();

    const int c0 = colbase + kq * 4;
    const int qd = (c0 >> 2) ^ fr;

    // ---- K -> EK = fp16(exp(-K))
    {
        f32x4 acc[4] = {};
        compute_acc16(ldsA, Wt16, 0, fr, kq, colbase, acc);
        const float4 bv = *(const float4*)&bias0[c0];
        #pragma unroll
        for (int m = 0; m < 4; ++m) {
            const int rl = m * 16 + fr;
            half4v o;
            o[0] = (_Float16)__expf(-(acc[m][0] + bv.x));
            o[1] = (_Float16)__expf(-(acc[m][1] + bv.y));
            o[2] = (_Float16)__expf(-(acc[m][2] + bv.z));
            o[3] = (_Float16)__expf(-(acc[m][3] + bv.w));
            ldsO[rl][qd] = *(uint2*)&o;
        }
    }
    __syncthreads();
    dense_out512(ldsO, (unsigned char*)OEK, row0, M, t);
    __syncthreads();

    // ---- Q -> EQ8 (low 4B) then V -> fp8 (high 4B)
    {
        f32x4 acc[4] = {};
        compute_acc16(ldsA, Wt16, 1, fr, kq, colbase, acc);
        const float4 bv = *(const float4*)&bias1[c0];
        #pragma unroll
        for (int m = 0; m < 4; ++m) {
            const int rl = m * 16 + fr;
            const float e0 = __expf(-(acc[m][0] + bv.x));
            const float e1 = __expf(-(acc[m][1] + bv.y));
            const float e2 = __expf(-(acc[m][2] + bv.z));
            const float e3 = __expf(-(acc[m][3] + bv.w));
            int p = 0;
            p = __builtin_amdgcn_cvt_pk_fp8_f32(e0, e1, p, false);
            p = __builtin_amdgcn_cvt_pk_fp8_f32(e2, e3, p, true);
            ((unsigned*)&ldsO[rl][qd])[0] = (unsigned)p;
        }
    }
    {
        f32x4 acc[4] = {};
        compute_acc16(ldsA, Wt16, 2, fr, kq, colbase, acc);
        const float4 bv = *(const float4*)&bias2[c0];
        #pragma unroll
        for (int m = 0; m < 4; ++m) {
            const int rl = m * 16 + fr;
            int p = 0;
            p = __builtin_amdgcn_cvt_pk_fp8_f32(acc[m][0] + bv.x,
                                                acc[m][1] + bv.y, p, false);
            p = __builtin_amdgcn_cvt_pk_fp8_f32(acc[m][2] + bv.z,
                                                acc[m][3] + bv.w, p, true);
            ((unsigned*)&ldsO[rl][qd])[1] = (unsigned)p;
        }
    }
    __syncthreads();
    dense_out512(ldsO, QV8, row0, M, t);
    __syncthreads();

    // ---- S (skip) fp16
    {
        f32x4 acc[4] = {};
        compute_acc16(ldsA, Wt16, 3, fr, kq, colbase, acc);
        const float4 bv = *(const float4*)&bias3[c0];
        #pragma unroll
        for (int m = 0; m < 4; ++m) {
            const int rl = m * 16 + fr;
            half4v o;
            o[0] = (_Float16)(acc[m][0] + bv.x);
            o[1] = (_Float16)(acc[m][1] + bv.y);
            o[2] = (_Float16)(acc[m][2] + bv.z);
            o[3] = (_Float16)(acc[m][3] + bv.w);
            ldsO[rl][qd] = *(uint2*)&o;
        }
    }
    __syncthreads();
    dense_out512(ldsO, (unsigned char*)OS, row0, M, t);
}

// ---------------------------------------------------------------------------
// Atomic-free CSR build (R20 structure: hierarchical scan).
// ---------------------------------------------------------------------------
__global__ __launch_bounds__(256) void pA_hist(const int* __restrict__ ei,
                                               int* __restrict__ ghA)
{
    __shared__ int lh[NBKT];
    const int t = threadIdx.x, b = blockIdx.x;
    if (t < NBKT) lh[t] = 0;
    __syncthreads();
    const int e0 = b * CHA;
    for (int i = t; i < CHA; i += 256)
        atomicAdd(&lh[ei[N_EDGES + e0 + i] >> 8], 1);
    __syncthreads();
    if (t < NBKT) ghA[t * NBA + b] = lh[t];
}

__global__ __launch_bounds__(256) void sc_p1(const int* __restrict__ g,
                                             int* __restrict__ bsum)
{
    __shared__ int red[256];
    const int t = threadIdx.x;
    const int i = blockIdx.x * 256 + t;
    red[t] = (i < NBKT * NBA) ? g[i] : 0;
    __syncthreads();
    for (int d = 128; d > 0; d >>= 1) {
        if (t < d) red[t] += red[t + d];
        __syncthreads();
    }
    if (t == 0) bsum[blockIdx.x] = red[0];
}

__global__ __launch_bounds__(128) void sc_p2(const int* __restrict__ bsum,
                                             int* __restrict__ bsoff,
                                             int* __restrict__ g)
{
    __shared__ int sc[128];
    const int t = threadIdx.x;
    const int v = (t < NSC) ? bsum[t] : 0;
    sc[t] = v;
    __syncthreads();
    #pragma unroll
    for (int d = 1; d < 128; d <<= 1) {
        const int a = (t >= d) ? sc[t - d] : 0;
        __syncthreads();
        sc[t] += a;
        __syncthreads();
    }
    if (t < NSC) bsoff[t] = sc[t] - v;
    if (t == 127) g[NBKT * NBA] = sc[127];   // = E
}

__global__ __launch_bounds__(256) void sc_p3(int* __restrict__ g,
                                             const int* __restrict__ bsoff)
{
    __shared__ int sc[256];
    const int t = threadIdx.x;
    const int i = blockIdx.x * 256 + t;
    const int v = (i < NBKT * NBA) ? g[i] : 0;
    sc[t] = v;
    __syncthreads();
    #pragma unroll
    for (int d = 1; d < 256; d <<= 1) {
        const int a = (t >= d) ? sc[t - d] : 0;
        __syncthreads();
        sc[t] += a;
        __syncthreads();
    }
    if (i < NBKT * NBA) g[i] = bsoff[blockIdx.x] + sc[t] - v;
}

__global__ __launch_bounds__(256) void pA_scat(const int* __restrict__ ei,
                                               const int* __restrict__ gbase,
                                               unsigned int* __restrict__ ebuf)
{
    __shared__ int cur[NBKT];
    const int t = threadIdx.x, b = blockIdx.x;
    if (t < NBKT) cur[t] = gbase[t * NBA + b];
    __syncthreads();
    const int e0 = b * CHA;
    for (int i = t; i < CHA; i += 256) {
        const unsigned d = (unsigned)ei[N_EDGES + e0 + i];
        const unsigned s = (unsigned)ei[e0 + i];
        const int pos = atomicAdd(&cur[d >> 8], 1);
        ebuf[pos] = (d << 16) | s;
    }
}

__global__ __launch_bounds__(256) void pB_build(const unsigned int* __restrict__ ebuf,
                                                const int* __restrict__ gbase,
                                                int* __restrict__ off,
                                                int* __restrict__ csr)
{
    __shared__ int lh[256], sc[256];
    const int t = threadIdx.x, b = blockIdx.x;
    const int beg = gbase[b * NBA];
    const int end = gbase[(b + 1) * NBA];
    lh[t] = 0;
    __syncthreads();
    for (int i = beg + t; i < end; i += 256)
        atomicAdd(&lh[(ebuf[i] >> 16) & 255], 1);
    __syncthreads();
    const int c = lh[t];
    sc[t] = c;
    __syncthreads();
    for (int d = 1; d < 256; d <<= 1) {
        const int v = (t >= d) ? sc[t - d] : 0;
        __syncthreads();
        sc[t] += v;
        __syncthreads();
    }
    const int excl = sc[t] - c;
    const int nd = b * 256 + t;
    if (nd <= N_NODES) off[nd] = beg + excl;
    __syncthreads();
    lh[t] = beg + excl;
    __syncthreads();
    for (int i = beg + t; i < end; i += 256) {
        const unsigned p = ebuf[i];
        const int pos = atomicAdd(&lh[(p >> 16) & 255], 1);
        csr[pos] = (int)(p & 0xFFFFu);
    }
}

// ---------------------------------------------------------------------------
// CSR aggregation (unchanged): 16B QV8 gathers, fp16 EK, rcp gate.
// ---------------------------------------------------------------------------
template<int FUSE>
__global__ __launch_bounds__(256) void agg_csr(
    const _Float16* __restrict__ EKb, const unsigned char* __restrict__ QV8,
    const int* __restrict__ off, const int* __restrict__ csr_src,
    _Float16* __restrict__ hSkip, _Float16* __restrict__ A16, int Nn)
{
    const int node = blockIdx.x * 4 + (threadIdx.x >> 6);
    if (node >= Nn) return;
    const int lane = threadIdx.x & 63;
    const int grp = lane >> 4;
    const int sub = lane & 15;
    const int q = sub * 8;

    const half8v ek8 = *(const half8v*)(EKb + (size_t)node * H + q);
    float ek[8];
    #pragma unroll
    for (int i = 0; i < 8; ++i) ek[i] = (float)ek8[i];
    float acc[8] = {};

    const int begin = off[node], end = off[node + 1];
    for (int j0 = begin; j0 < end; j0 += 64) {
        const int nrem = end - j0;
        const int nk = nrem < 64 ? nrem : 64;
        const int sv = (lane < nk) ? csr_src[j0 + lane] : 0;
        #pragma unroll 4
        for (int k = 0; k < nk; k += 4) {
            const int myk = k + grp;
            const int s = __shfl(sv, myk < nk ? myk : 0);
            if (myk < nk) {
                const uint4 p = *(const uint4*)(QV8 + (size_t)s * 256 + sub * 16);
                const f32x2 ea = __builtin_amdgcn_cvt_pk_f32_fp8(p.x, false);
                const f32x2 eb = __builtin_amdgcn_cvt_pk_f32_fp8(p.x, true);
                const f32x2 va = __builtin_amdgcn_cvt_pk_f32_fp8(p.y, false);
                const f32x2 vb = __builtin_amdgcn_cvt_pk_f32_fp8(p.y, true);
                const f32x2 ec = __builtin_amdgcn_cvt_pk_f32_fp8(p.z, false);
                const f32x2 ed = __builtin_amdgcn_cvt_pk_f32_fp8(p.z, true);
                const f32x2 vc = __builtin_amdgcn_cvt_pk_f32_fp8(p.w, false);
                const f32x2 vd = __builtin_amdgcn_cvt_pk_f32_fp8(p.w, true);
                acc[0] = fmaf(va[0], __builtin_amdgcn_rcpf(fmaf(ek[0], ea[0], 1.f)), acc[0]);
                acc[1] = fmaf(va[1], __builtin_amdgcn_rcpf(fmaf(ek[1], ea[1], 1.f)), acc[1]);
                acc[2] = fmaf(vb[0], __builtin_amdgcn_rcpf(fmaf(ek[2], eb[0], 1.f)), acc[2]);
                acc[3] = fmaf(vb[1], __builtin_amdgcn_rcpf(fmaf(ek[3], eb[1], 1.f)), acc[3]);
                acc[4] = fmaf(vc[0], __builtin_amdgcn_rcpf(fmaf(ek[4], ec[0], 1.f)), acc[4]);
                acc[5] = fmaf(vc[1], __builtin_amdgcn_rcpf(fmaf(ek[5], ec[1], 1.f)), acc[5]);
                acc[6] = fmaf(vd[0], __builtin_amdgcn_rcpf(fmaf(ek[6], ed[0], 1.f)), acc[6]);
                acc[7] = fmaf(vd[1], __builtin_amdgcn_rcpf(fmaf(ek[7], ed[1], 1.f)), acc[7]);
            }
        }
    }
    #pragma unroll
    for (int i = 0; i < 8; ++i) {
        acc[i] += __shfl_xor(acc[i], 16);
        acc[i] += __shfl_xor(acc[i], 32);
    }
    if (grp == 0) {
        const half8v sk8 = *(const half8v*)(hSkip + (size_t)node * H + q);
        half8v hv;
        if (FUSE) {
            #pragma unroll
            for (int j = 0; j < 8; ++j)
                hv[j] = (_Float16)fmaxf((float)sk8[j] + acc[j], 0.f);
            *(half8v*)&A16[(size_t)node * 128 + q] = hv;
        } else {
            #pragma unroll
            for (int j = 0; j < 8; ++j)
                hv[j] = (_Float16)((float)sk8[j] + acc[j]);
            *(half8v*)&hSkip[(size_t)node * H + q] = hv;
        }
    }
}

// ---------------------------------------------------------------------------
// Fused pool + MLP: one block per graph.  128 threads sum the graph segment
// (dim t per thread) into LDS, then wave 0 runs the 128->64->1 MLP head.
// Removes the hg buffer, its memset, and the cross-block atomics.
// ---------------------------------------------------------------------------
__global__ __launch_bounds__(128) void pool_mlp(
    const _Float16* __restrict__ h, const int* __restrict__ gstart,
    const float* __restrict__ W4, const float* __restrict__ b4,
    const float* __restrict__ W5, const float* __restrict__ b5,
    float* __restrict__ out)
{
    const int g = blockIdx.x;
    const int t = threadIdx.x;
    __shared__ float hrow[H];
    const int b0 = gstart[g], b1 = gstart[g + 1];
    float acc = 0.f;
    for (int n = b0; n < b1; ++n) acc += (float)h[(size_t)n * H + t];
    hrow[t] = acc;
    __syncthreads();
    if (t < 64) {
        float s = b4[t];
        #pragma unroll 8
        for (int k = 0; k < H; ++k) s += hrow[k] * W4[(size_t)k * 64 + t];
        s = fmaxf(s, 0.f) * W5[t];
        #pragma unroll
        for (int o = 32; o > 0; o >>= 1) s += __shfl_down(s, o);
        if (t == 0) out[g] = 1.f / (1.f + __expf(-(s + b5[0])));
    }
}

// ---------------------------------------------------------------------------
extern "C" void kernel_launch(void* const* d_in, const int* in_sizes, int n_in,
                              void* d_out, int out_size, void* d_ws, size_t ws_size,
                              hipStream_t stream)
{
    const float* x = (const float*)d_in[0];
    const float *Wk[3], *bk[3], *Wq[3], *bq[3], *Wv[3], *bv[3], *Wsk[3], *bs[3];
    for (int l = 0; l < 3; ++l) {
        const int base = 2 + l * 8;
        Wk[l]  = (const float*)d_in[base + 0]; bk[l] = (const float*)d_in[base + 1];
        Wq[l]  = (const float*)d_in[base + 2]; bq[l] = (const float*)d_in[base + 3];
        Wv[l]  = (const float*)d_in[base + 4]; bv[l] = (const float*)d_in[base + 5];
        Wsk[l] = (const float*)d_in[base + 6]; bs[l] = (const float*)d_in[base + 7];
    }
    const float* W4 = (const float*)d_in[26];
    const float* b4 = (const float*)d_in[27];
    const float* W5 = (const float*)d_in[28];
    const float* b5 = (const float*)d_in[29];
    const int* ei    = (const int*)d_in[30];
    const int* batch = (const int*)d_in[31];
    float* out = (float*)d_out;

    const size_t NH = (size_t)N_NODES * H;
    const size_t AH = (size_t)MP * 128;
    const size_t WH3 = (size_t)3 * 512 * 128;
    _Float16*      EKb  = (_Float16*)d_ws;                    // NH halfs
    _Float16*      hbuf = EKb + NH;                           // NH halfs
    unsigned char* QV8  = (unsigned char*)(hbuf + NH);        // 2*NH bytes
    _Float16*      A16  = (_Float16*)(QV8 + 2 * NH);          // AH halfs
    _Float16*      Wt16 = A16 + AH;                           // WH3 halfs
    int*           off  = (int*)(Wt16 + WH3);                 // N+1
    int*           csr  = off + (N_NODES + 1);                // E
    unsigned int*  ebuf = (unsigned int*)(csr + N_EDGES);     // E
    int*           ghA  = (int*)(ebuf + N_EDGES);             // NBKT*NBA+1
    int*           gst  = ghA + (NBKT * NBA + 1);             // G+1
    int*           bsum = gst + (N_GRAPHS + 1);               // NSC
    int*           bsoff= bsum + NSC;                         // NSC
    const size_t need = 2 * NH * sizeof(unsigned char)
                      + (2 * NH + AH + WH3) * sizeof(_Float16)
                      + (size_t)(N_NODES + 1 + 2 * N_EDGES + NBKT * NBA + 1
                                 + N_GRAPHS + 1 + 2 * NSC) * sizeof(int);
    if (ws_size < need) return;

    const int ablk = (N_NODES + 3) / 4;
    const int ggrid = MP / 64;           // 782 blocks x 512 threads

    // ---- CSR build (hierarchical scan) + fused W/A/gstart prep
    pA_hist<<<NBA, 256, 0, stream>>>(ei, ghA);
    sc_p1<<<NSC, 256, 0, stream>>>(ghA, bsum);
    sc_p2<<<1, 128, 0, stream>>>(bsum, bsoff, ghA);
    sc_p3<<<NSC, 256, 0, stream>>>(ghA, bsoff);
    pA_scat<<<NBA, 256, 0, stream>>>(ei, ghA, ebuf);
    pB_build<<<NBKT, 256, 0, stream>>>(ebuf, ghA, off, csr);
    WPtrs wp;
    for (int l = 0; l < 3; ++l) {
        wp.w[l * 4 + 0] = Wk[l];
        wp.w[l * 4 + 1] = Wq[l];
        wp.w[l * 4 + 2] = Wv[l];
        wp.w[l * 4 + 3] = Wsk[l];
    }
    conv_prep<<<768 + CABLK + GSBLK, 256, 0, stream>>>(wp, x, batch, Wt16, A16, gst);

    // ---- Layer 1
    gemm_mfma<<<ggrid, 512, 0, stream>>>(A16, Wt16,
        bk[0], bq[0], bv[0], bs[0], EKb, QV8, hbuf, N_NODES);
    agg_csr<1><<<ablk, 256, 0, stream>>>(EKb, QV8, off, csr, hbuf, A16, N_NODES);

    // ---- Layer 2
    gemm_mfma<<<ggrid, 512, 0, stream>>>(A16, Wt16 + 512 * 128,
        bk[1], bq[1], bv[1], bs[1], EKb, QV8, hbuf, N_NODES);
    agg_csr<1><<<ablk, 256, 0, stream>>>(EKb, QV8, off, csr, hbuf, A16, N_NODES);

    // ---- Layer 3
    gemm_mfma<<<ggrid, 512, 0, stream>>>(A16, Wt16 + 1024 * 128,
        bk[2], bq[2], bv[2], bs[2], EKb, QV8, hbuf, N_NODES);
    agg_csr<0><<<ablk, 256, 0, stream>>>(EKb, QV8, off, csr, hbuf, A16, N_NODES);

    // ---- Fused pool + MLP
    pool_mlp<<<N_GRAPHS, 128, 0, stream>>>(hbuf, gst, W4, b4, W5, b5, out);
}

// Round 22
// 265.276 us; speedup vs baseline: 1.1311x; 1.1311x over previous
//
#include <hip/hip_runtime.h>

#define N_NODES 50000
#define N_EDGES 800000
#define N_GRAPHS 256
#define DIN 126
#define H 128
#define MP 50048           // N_NODES padded to 128
#define NBKT 196           // coarse buckets = dst>>8
#define NBA 100            // phase-A blocks
#define CHA 8000           // edges per phase-A block (100*8000 = 800000)
#define NSC 77             // ceil(NBKT*NBA/256) scan chunks
#define CABLK 3128         // (MP*16)/256 conv_A blocks
#define GSBLK 196          // ceil(N_NODES/256) gstart blocks

typedef __attribute__((ext_vector_type(8))) _Float16 half8v;
typedef __attribute__((ext_vector_type(4))) _Float16 half4v;
typedef __attribute__((ext_vector_type(4))) float f32x4;
typedef __attribute__((ext_vector_type(2))) float f32x2;

// ---------------------------------------------------------------------------
// Fused prep: blocks [0,768) convert W (3 layers); [768, 768+CABLK) convert
// layer-1 A; [768+CABLK, +GSBLK) build graph segment starts.
// ---------------------------------------------------------------------------
struct WPtrs { const float* w[12]; };

__global__ __launch_bounds__(256) void conv_prep(WPtrs P, const float* __restrict__ X,
                                                 const int* __restrict__ batch,
                                                 _Float16* __restrict__ Wt16,
                                                 _Float16* __restrict__ A16,
                                                 int* __restrict__ gstart)
{
    if (blockIdx.x < 768) {
        const int t = blockIdx.x * 256 + threadIdx.x;
        const int layer = t >> 16;
        const int r = t & 65535;
        const int n = r >> 7, k = r & 127;
        const int mtx = n >> 7, cc = n & 127;
        const int Kd = (layer == 0) ? DIN : H;
        const float* W = P.w[layer * 4 + mtx];
        const float v = (k < Kd) ? W[(size_t)k * 128 + cc] : 0.f;
        Wt16[t] = (_Float16)v;
    } else if (blockIdx.x < 768 + CABLK) {
        const int t = (blockIdx.x - 768) * 256 + threadIdx.x;
        const int row = t >> 4;
        if (row >= MP) return;
        const int k0 = (t & 15) * 8;
        half8v v8;
        #pragma unroll
        for (int j = 0; j < 8; ++j) {
            const int k = k0 + j;
            float v = 0.f;
            if (row < N_NODES && k < DIN) v = X[(size_t)row * DIN + k];
            v8[j] = (_Float16)v;
        }
        *(half8v*)&A16[(size_t)row * 128 + k0] = v8;
    } else {
        const int n = (blockIdx.x - 768 - CABLK) * 256 + threadIdx.x;
        if (n >= N_NODES) return;
        const int b = batch[n];
        const int bp = (n == 0) ? -1 : batch[n - 1];
        for (int g = bp + 1; g <= b; ++g) gstart[g] = n;
        if (n == N_NODES - 1)
            for (int g = b + 1; g <= N_GRAPHS; ++g) gstart[g] = N_NODES;
    }
}

// ---------------------------------------------------------------------------
// MFMA GEMM (frozen since R18): one block = 64 rows x all 4 matrices,
// 512 threads, A staged once, LDS-staged dense epilogue.
// ---------------------------------------------------------------------------
__device__ __forceinline__ void dense_out512(const uint2 (&ldsO)[64][32],
                                             unsigned char* __restrict__ dst,
                                             int row0, int M, int t)
{
    #pragma unroll
    for (int i = 0; i < 2; ++i) {
        const int idx = i * 512 + t;
        const int rr = idx >> 4, c16 = idx & 15;
        const int ch = c16 ^ ((rr & 15) >> 1);
        const uint2 a = ldsO[rr][2 * ch];
        const uint2 b = ldsO[rr][2 * ch + 1];
        if (row0 + rr < M) {
            uint4 o;
            if (rr & 1) { o.x = b.x; o.y = b.y; o.z = a.x; o.w = a.y; }
            else        { o.x = a.x; o.y = a.y; o.z = b.x; o.w = b.y; }
            *(uint4*)(dst + (size_t)(row0 + rr) * 256 + c16 * 16) = o;
        }
    }
}

__device__ __forceinline__ void compute_acc16(const _Float16 (&ldsA)[2][64 * 64],
                                              const _Float16* __restrict__ Wt16,
                                              int mtx, int fr, int kq, int colbase,
                                              f32x4 (&acc)[4])
{
    #pragma unroll
    for (int step = 0; step < 4; ++step) {
        const int kg = step * 4 + kq;
        const int kh = kg >> 3, kk = kg & 7;
        half8v a[4];
        #pragma unroll
        for (int m = 0; m < 4; ++m) {
            const int ar = m * 16 + fr;
            const int slot = kk ^ (ar & 7);
            a[m] = *(const half8v*)&ldsA[kh][ar * 64 + slot * 8];
        }
        const size_t wo = (size_t)(mtx * 128 + colbase + fr) * 128 + kg * 8;
        const half8v w = *(const half8v*)&Wt16[wo];
        #pragma unroll
        for (int m = 0; m < 4; ++m)
            acc[m] = __builtin_amdgcn_mfma_f32_16x16x32_f16(w, a[m], acc[m], 0, 0, 0);
    }
}

__global__ __launch_bounds__(512) void gemm_mfma(
    const _Float16* __restrict__ A16, const _Float16* __restrict__ Wt16,
    const float* __restrict__ bias0, const float* __restrict__ bias1,
    const float* __restrict__ bias2, const float* __restrict__ bias3,
    _Float16* __restrict__ OEK, unsigned char* __restrict__ QV8,
    _Float16* __restrict__ OS, int M)
{
    __shared__ _Float16 ldsA[2][64 * 64];  // 16KB
    __shared__ uint2 ldsO[64][32];         // 16KB
    const int t = threadIdx.x;
    const int l = t & 63, w = t >> 6;
    const int row0 = blockIdx.x * 64;
    const int fr = l & 15;
    const int kq = l >> 4;
    const int colbase = w * 16;

    #pragma unroll
    for (int i = 0; i < 2; ++i) {
        const int gi = i * 512 + t;
        const int kh = gi >> 9;
        const int r = (gi >> 3) & 63;
        const int j = gi & 7;
        const int slot = j ^ (r & 7);
        *(half8v*)&ldsA[kh][r * 64 + slot * 8] =
            *(const half8v*)&A16[(size_t)(row0 + r) * 128 + kh * 64 + j * 8];
    }
    __syncthreads();

    const int c0 = colbase + kq * 4;
    const int qd = (c0 >> 2) ^ fr;

    // ---- K -> EK = fp16(exp(-K))
    {
        f32x4 acc[4] = {};
        compute_acc16(ldsA, Wt16, 0, fr, kq, colbase, acc);
        const float4 bv = *(const float4*)&bias0[c0];
        #pragma unroll
        for (int m = 0; m < 4; ++m) {
            const int rl = m * 16 + fr;
            half4v o;
            o[0] = (_Float16)__expf(-(acc[m][0] + bv.x));
            o[1] = (_Float16)__expf(-(acc[m][1] + bv.y));
            o[2] = (_Float16)__expf(-(acc[m][2] + bv.z));
            o[3] = (_Float16)__expf(-(acc[m][3] + bv.w));
            ldsO[rl][qd] = *(uint2*)&o;
        }
    }
    __syncthreads();
    dense_out512(ldsO, (unsigned char*)OEK, row0, M, t);
    __syncthreads();

    // ---- Q -> EQ8 (low 4B) then V -> fp8 (high 4B)
    {
        f32x4 acc[4] = {};
        compute_acc16(ldsA, Wt16, 1, fr, kq, colbase, acc);
        const float4 bv = *(const float4*)&bias1[c0];
        #pragma unroll
        for (int m = 0; m < 4; ++m) {
            const int rl = m * 16 + fr;
            const float e0 = __expf(-(acc[m][0] + bv.x));
            const float e1 = __expf(-(acc[m][1] + bv.y));
            const float e2 = __expf(-(acc[m][2] + bv.z));
            const float e3 = __expf(-(acc[m][3] + bv.w));
            int p = 0;
            p = __builtin_amdgcn_cvt_pk_fp8_f32(e0, e1, p, false);
            p = __builtin_amdgcn_cvt_pk_fp8_f32(e2, e3, p, true);
            ((unsigned*)&ldsO[rl][qd])[0] = (unsigned)p;
        }
    }
    {
        f32x4 acc[4] = {};
        compute_acc16(ldsA, Wt16, 2, fr, kq, colbase, acc);
        const float4 bv = *(const float4*)&bias2[c0];
        #pragma unroll
        for (int m = 0; m < 4; ++m) {
            const int rl = m * 16 + fr;
            int p = 0;
            p = __builtin_amdgcn_cvt_pk_fp8_f32(acc[m][0] + bv.x,
                                                acc[m][1] + bv.y, p, false);
            p = __builtin_amdgcn_cvt_pk_fp8_f32(acc[m][2] + bv.z,
                                                acc[m][3] + bv.w, p, true);
            ((unsigned*)&ldsO[rl][qd])[1] = (unsigned)p;
        }
    }
    __syncthreads();
    dense_out512(ldsO, QV8, row0, M, t);
    __syncthreads();

    // ---- S (skip) fp16
    {
        f32x4 acc[4] = {};
        compute_acc16(ldsA, Wt16, 3, fr, kq, colbase, acc);
        const float4 bv = *(const float4*)&bias3[c0];
        #pragma unroll
        for (int m = 0; m < 4; ++m) {
            const int rl = m * 16 + fr;
            half4v o;
            o[0] = (_Float16)(acc[m][0] + bv.x);
            o[1] = (_Float16)(acc[m][1] + bv.y);
            o[2] = (_Float16)(acc[m][2] + bv.z);
            o[3] = (_Float16)(acc[m][3] + bv.w);
            ldsO[rl][qd] = *(uint2*)&o;
        }
    }
    __syncthreads();
    dense_out512(ldsO, (unsigned char*)OS, row0, M, t);
}

// ---------------------------------------------------------------------------
// Atomic-free CSR build (R20 structure: hierarchical scan).
// ---------------------------------------------------------------------------
__global__ __launch_bounds__(256) void pA_hist(const int* __restrict__ ei,
                                               int* __restrict__ ghA)
{
    __shared__ int lh[NBKT];
    const int t = threadIdx.x, b = blockIdx.x;
    if (t < NBKT) lh[t] = 0;
    __syncthreads();
    const int e0 = b * CHA;
    for (int i = t; i < CHA; i += 256)
        atomicAdd(&lh[ei[N_EDGES + e0 + i] >> 8], 1);
    __syncthreads();
    if (t < NBKT) ghA[t * NBA + b] = lh[t];
}

__global__ __launch_bounds__(256) void sc_p1(const int* __restrict__ g,
                                             int* __restrict__ bsum)
{
    __shared__ int red[256];
    const int t = threadIdx.x;
    const int i = blockIdx.x * 256 + t;
    red[t] = (i < NBKT * NBA) ? g[i] : 0;
    __syncthreads();
    for (int d = 128; d > 0; d >>= 1) {
        if (t < d) red[t] += red[t + d];
        __syncthreads();
    }
    if (t == 0) bsum[blockIdx.x] = red[0];
}

__global__ __launch_bounds__(128) void sc_p2(const int* __restrict__ bsum,
                                             int* __restrict__ bsoff,
                                             int* __restrict__ g)
{
    __shared__ int sc[128];
    const int t = threadIdx.x;
    const int v = (t < NSC) ? bsum[t] : 0;
    sc[t] = v;
    __syncthreads();
    #pragma unroll
    for (int d = 1; d < 128; d <<= 1) {
        const int a = (t >= d) ? sc[t - d] : 0;
        __syncthreads();
        sc[t] += a;
        __syncthreads();
    }
    if (t < NSC) bsoff[t] = sc[t] - v;
    if (t == 127) g[NBKT * NBA] = sc[127];   // = E
}

__global__ __launch_bounds__(256) void sc_p3(int* __restrict__ g,
                                             const int* __restrict__ bsoff)
{
    __shared__ int sc[256];
    const int t = threadIdx.x;
    const int i = blockIdx.x * 256 + t;
    const int v = (i < NBKT * NBA) ? g[i] : 0;
    sc[t] = v;
    __syncthreads();
    #pragma unroll
    for (int d = 1; d < 256; d <<= 1) {
        const int a = (t >= d) ? sc[t - d] : 0;
        __syncthreads();
        sc[t] += a;
        __syncthreads();
    }
    if (i < NBKT * NBA) g[i] = bsoff[blockIdx.x] + sc[t] - v;
}

__global__ __launch_bounds__(256) void pA_scat(const int* __restrict__ ei,
                                               const int* __restrict__ gbase,
                                               unsigned int* __restrict__ ebuf)
{
    __shared__ int cur[NBKT];
    const int t = threadIdx.x, b = blockIdx.x;
    if (t < NBKT) cur[t] = gbase[t * NBA + b];
    __syncthreads();
    const int e0 = b * CHA;
    for (int i = t; i < CHA; i += 256) {
        const unsigned d = (unsigned)ei[N_EDGES + e0 + i];
        const unsigned s = (unsigned)ei[e0 + i];
        const int pos = atomicAdd(&cur[d >> 8], 1);
        ebuf[pos] = (d << 16) | s;
    }
}

__global__ __launch_bounds__(256) void pB_build(const unsigned int* __restrict__ ebuf,
                                                const int* __restrict__ gbase,
                                                int* __restrict__ off,
                                                int* __restrict__ csr)
{
    __shared__ int lh[256], sc[256];
    const int t = threadIdx.x, b = blockIdx.x;
    const int beg = gbase[b * NBA];
    const int end = gbase[(b + 1) * NBA];
    lh[t] = 0;
    __syncthreads();
    for (int i = beg + t; i < end; i += 256)
        atomicAdd(&lh[(ebuf[i] >> 16) & 255], 1);
    __syncthreads();
    const int c = lh[t];
    sc[t] = c;
    __syncthreads();
    for (int d = 1; d < 256; d <<= 1) {
        const int v = (t >= d) ? sc[t - d] : 0;
        __syncthreads();
        sc[t] += v;
        __syncthreads();
    }
    const int excl = sc[t] - c;
    const int nd = b * 256 + t;
    if (nd <= N_NODES) off[nd] = beg + excl;
    __syncthreads();
    lh[t] = beg + excl;
    __syncthreads();
    for (int i = beg + t; i < end; i += 256) {
        const unsigned p = ebuf[i];
        const int pos = atomicAdd(&lh[(p >> 16) & 255], 1);
        csr[pos] = (int)(p & 0xFFFFu);
    }
}

// ---------------------------------------------------------------------------
// CSR aggregation (frozen since R16): 16B QV8 gathers, fp16 EK, rcp gate.
// ---------------------------------------------------------------------------
template<int FUSE>
__global__ __launch_bounds__(256) void agg_csr(
    const _Float16* __restrict__ EKb, const unsigned char* __restrict__ QV8,
    const int* __restrict__ off, const int* __restrict__ csr_src,
    _Float16* __restrict__ hSkip, _Float16* __restrict__ A16, int Nn)
{
    const int node = blockIdx.x * 4 + (threadIdx.x >> 6);
    if (node >= Nn) return;
    const int lane = threadIdx.x & 63;
    const int grp = lane >> 4;
    const int sub = lane & 15;
    const int q = sub * 8;

    const half8v ek8 = *(const half8v*)(EKb + (size_t)node * H + q);
    float ek[8];
    #pragma unroll
    for (int i = 0; i < 8; ++i) ek[i] = (float)ek8[i];
    float acc[8] = {};

    const int begin = off[node], end = off[node + 1];
    for (int j0 = begin; j0 < end; j0 += 64) {
        const int nrem = end - j0;
        const int nk = nrem < 64 ? nrem : 64;
        const int sv = (lane < nk) ? csr_src[j0 + lane] : 0;
        #pragma unroll 4
        for (int k = 0; k < nk; k += 4) {
            const int myk = k + grp;
            const int s = __shfl(sv, myk < nk ? myk : 0);
            if (myk < nk) {
                const uint4 p = *(const uint4*)(QV8 + (size_t)s * 256 + sub * 16);
                const f32x2 ea = __builtin_amdgcn_cvt_pk_f32_fp8(p.x, false);
                const f32x2 eb = __builtin_amdgcn_cvt_pk_f32_fp8(p.x, true);
                const f32x2 va = __builtin_amdgcn_cvt_pk_f32_fp8(p.y, false);
                const f32x2 vb = __builtin_amdgcn_cvt_pk_f32_fp8(p.y, true);
                const f32x2 ec = __builtin_amdgcn_cvt_pk_f32_fp8(p.z, false);
                const f32x2 ed = __builtin_amdgcn_cvt_pk_f32_fp8(p.z, true);
                const f32x2 vc = __builtin_amdgcn_cvt_pk_f32_fp8(p.w, false);
                const f32x2 vd = __builtin_amdgcn_cvt_pk_f32_fp8(p.w, true);
                acc[0] = fmaf(va[0], __builtin_amdgcn_rcpf(fmaf(ek[0], ea[0], 1.f)), acc[0]);
                acc[1] = fmaf(va[1], __builtin_amdgcn_rcpf(fmaf(ek[1], ea[1], 1.f)), acc[1]);
                acc[2] = fmaf(vb[0], __builtin_amdgcn_rcpf(fmaf(ek[2], eb[0], 1.f)), acc[2]);
                acc[3] = fmaf(vb[1], __builtin_amdgcn_rcpf(fmaf(ek[3], eb[1], 1.f)), acc[3]);
                acc[4] = fmaf(vc[0], __builtin_amdgcn_rcpf(fmaf(ek[4], ec[0], 1.f)), acc[4]);
                acc[5] = fmaf(vc[1], __builtin_amdgcn_rcpf(fmaf(ek[5], ec[1], 1.f)), acc[5]);
                acc[6] = fmaf(vd[0], __builtin_amdgcn_rcpf(fmaf(ek[6], ed[0], 1.f)), acc[6]);
                acc[7] = fmaf(vd[1], __builtin_amdgcn_rcpf(fmaf(ek[7], ed[1], 1.f)), acc[7]);
            }
        }
    }
    #pragma unroll
    for (int i = 0; i < 8; ++i) {
        acc[i] += __shfl_xor(acc[i], 16);
        acc[i] += __shfl_xor(acc[i], 32);
    }
    if (grp == 0) {
        const half8v sk8 = *(const half8v*)(hSkip + (size_t)node * H + q);
        half8v hv;
        if (FUSE) {
            #pragma unroll
            for (int j = 0; j < 8; ++j)
                hv[j] = (_Float16)fmaxf((float)sk8[j] + acc[j], 0.f);
            *(half8v*)&A16[(size_t)node * 128 + q] = hv;
        } else {
            #pragma unroll
            for (int j = 0; j < 8; ++j)
                hv[j] = (_Float16)((float)sk8[j] + acc[j]);
            *(half8v*)&hSkip[(size_t)node * H + q] = hv;
        }
    }
}

// ---------------------------------------------------------------------------
// Pool (R20-proven split form, widened to 8 partitions) + MLP.
// ---------------------------------------------------------------------------
__global__ __launch_bounds__(128) void pool_seg(const _Float16* __restrict__ h,
                                                const int* __restrict__ gstart,
                                                float* __restrict__ hg)
{
    const int g = blockIdx.x;
    const int part = blockIdx.y;
    const int t = threadIdx.x;
    const int b0 = gstart[g], b1 = gstart[g + 1];
    float acc = 0.f;
    for (int n = b0 + part; n < b1; n += 8) acc += (float)h[(size_t)n * H + t];
    atomicAdd(&hg[(size_t)g * H + t], acc);
}

__global__ __launch_bounds__(64) void mlp_kernel(
    const float* __restrict__ hg,
    const float* __restrict__ W4, const float* __restrict__ b4,
    const float* __restrict__ W5, const float* __restrict__ b5,
    float* __restrict__ out)
{
    const int g = blockIdx.x;
    const int c = threadIdx.x;
    __shared__ float hrow[H];
    for (int k = c; k < H; k += 64) hrow[k] = hg[(size_t)g * H + k];
    __syncthreads();
    float s = b4[c];
    #pragma unroll 8
    for (int k = 0; k < H; ++k) s += hrow[k] * W4[(size_t)k * 64 + c];
    s = fmaxf(s, 0.f) * W5[c];
    #pragma unroll
    for (int o = 32; o > 0; o >>= 1) s += __shfl_down(s, o);
    if (c == 0) out[g] = 1.f / (1.f + __expf(-(s + b5[0])));
}

// ---------------------------------------------------------------------------
extern "C" void kernel_launch(void* const* d_in, const int* in_sizes, int n_in,
                              void* d_out, int out_size, void* d_ws, size_t ws_size,
                              hipStream_t stream)
{
    const float* x = (const float*)d_in[0];
    const float *Wk[3], *bk[3], *Wq[3], *bq[3], *Wv[3], *bv[3], *Wsk[3], *bs[3];
    for (int l = 0; l < 3; ++l) {
        const int base = 2 + l * 8;
        Wk[l]  = (const float*)d_in[base + 0]; bk[l] = (const float*)d_in[base + 1];
        Wq[l]  = (const float*)d_in[base + 2]; bq[l] = (const float*)d_in[base + 3];
        Wv[l]  = (const float*)d_in[base + 4]; bv[l] = (const float*)d_in[base + 5];
        Wsk[l] = (const float*)d_in[base + 6]; bs[l] = (const float*)d_in[base + 7];
    }
    const float* W4 = (const float*)d_in[26];
    const float* b4 = (const float*)d_in[27];
    const float* W5 = (const float*)d_in[28];
    const float* b5 = (const float*)d_in[29];
    const int* ei    = (const int*)d_in[30];
    const int* batch = (const int*)d_in[31];
    float* out = (float*)d_out;

    const size_t NH = (size_t)N_NODES * H;
    const size_t AH = (size_t)MP * 128;
    const size_t WH3 = (size_t)3 * 512 * 128;
    _Float16*      EKb  = (_Float16*)d_ws;                    // NH halfs
    _Float16*      hbuf = EKb + NH;                           // NH halfs
    unsigned char* QV8  = (unsigned char*)(hbuf + NH);        // 2*NH bytes
    _Float16*      A16  = (_Float16*)(QV8 + 2 * NH);          // AH halfs
    _Float16*      Wt16 = A16 + AH;                           // WH3 halfs
    float*         hg   = (float*)(Wt16 + WH3);               // G*H (zeroed)
    int*           off  = (int*)(hg + (size_t)N_GRAPHS * H);  // N+1
    int*           csr  = off + (N_NODES + 1);                // E
    unsigned int*  ebuf = (unsigned int*)(csr + N_EDGES);     // E
    int*           ghA  = (int*)(ebuf + N_EDGES);             // NBKT*NBA+1
    int*           gst  = ghA + (NBKT * NBA + 1);             // G+1
    int*           bsum = gst + (N_GRAPHS + 1);               // NSC
    int*           bsoff= bsum + NSC;                         // NSC
    const size_t need = (size_t)N_GRAPHS * H * sizeof(float)
                      + 2 * NH * sizeof(unsigned char)
                      + (2 * NH + AH + WH3) * sizeof(_Float16)
                      + (size_t)(N_NODES + 1 + 2 * N_EDGES + NBKT * NBA + 1
                                 + N_GRAPHS + 1 + 2 * NSC) * sizeof(int);
    if (ws_size < need) return;

    const int ablk = (N_NODES + 3) / 4;
    const int ggrid = MP / 64;           // 782 blocks x 512 threads
    const dim3 pgrid(N_GRAPHS, 8);

    // ---- memset: hg only (pool accumulator)
    hipMemsetAsync(hg, 0, (size_t)N_GRAPHS * H * sizeof(float), stream);

    // ---- CSR build (hierarchical scan) + fused W/A/gstart prep
    pA_hist<<<NBA, 256, 0, stream>>>(ei, ghA);
    sc_p1<<<NSC, 256, 0, stream>>>(ghA, bsum);
    sc_p2<<<1, 128, 0, stream>>>(bsum, bsoff, ghA);
    sc_p3<<<NSC, 256, 0, stream>>>(ghA, bsoff);
    pA_scat<<<NBA, 256, 0, stream>>>(ei, ghA, ebuf);
    pB_build<<<NBKT, 256, 0, stream>>>(ebuf, ghA, off, csr);
    WPtrs wp;
    for (int l = 0; l < 3; ++l) {
        wp.w[l * 4 + 0] = Wk[l];
        wp.w[l * 4 + 1] = Wq[l];
        wp.w[l * 4 + 2] = Wv[l];
        wp.w[l * 4 + 3] = Wsk[l];
    }
    conv_prep<<<768 + CABLK + GSBLK, 256, 0, stream>>>(wp, x, batch, Wt16, A16, gst);

    // ---- Layer 1
    gemm_mfma<<<ggrid, 512, 0, stream>>>(A16, Wt16,
        bk[0], bq[0], bv[0], bs[0], EKb, QV8, hbuf, N_NODES);
    agg_csr<1><<<ablk, 256, 0, stream>>>(EKb, QV8, off, csr, hbuf, A16, N_NODES);

    // ---- Layer 2
    gemm_mfma<<<ggrid, 512, 0, stream>>>(A16, Wt16 + 512 * 128,
        bk[1], bq[1], bv[1], bs[1], EKb, QV8, hbuf, N_NODES);
    agg_csr<1><<<ablk, 256, 0, stream>>>(EKb, QV8, off, csr, hbuf, A16, N_NODES);

    // ---- Layer 3
    gemm_mfma<<<ggrid, 512, 0, stream>>>(A16, Wt16 + 1024 * 128,
        bk[2], bq[2], bv[2], bs[2], EKb, QV8, hbuf, N_NODES);
    agg_csr<0><<<ablk, 256, 0, stream>>>(EKb, QV8, off, csr, hbuf, A16, N_NODES);

    // ---- Pool + MLP
    pool_seg<<<pgrid, 128, 0, stream>>>(hbuf, gst, hg);
    mlp_kernel<<<N_GRAPHS, 64, 0, stream>>>(hg, W4, b4, W5, b5, out);
}